// Round 10
// baseline (322.908 us; speedup 1.0000x reference)
//
#include <hip/hip_runtime.h>
#include <hip/hip_bf16.h>
#include <stdint.h>

typedef __bf16 bf16_t;
typedef __bf16 bf16x8 __attribute__((ext_vector_type(8)));
typedef float f32x4 __attribute__((ext_vector_type(4)));
typedef float f32x16 __attribute__((ext_vector_type(16)));

#define S_TOK 8192
#define DIM   1280
#define NH    16
#define HD    80
#define LSEQ  1024
#define N_QKV 3840

// async global->LDS, 16B per lane; lds dest is wave-uniform base + lane*16
__device__ __forceinline__ void gload16(const bf16_t* g, void* l) {
  __builtin_amdgcn_global_load_lds(
      (__attribute__((address_space(1))) uint32_t*)g,
      (__attribute__((address_space(3))) uint32_t*)l, 16, 0, 0);
}

// ---------------- fp32 -> bf16 convert (hidden_states) ----------------
__global__ __launch_bounds__(256) void k_conv_bf16(const float* __restrict__ in,
                                                   bf16_t* __restrict__ out) {
  int g = blockIdx.x * 256 + threadIdx.x;
  const float4* p = reinterpret_cast<const float4*>(in) + (size_t)g * 2;
  float4 v0 = p[0], v1 = p[1];
  bf16x8 o;
  o[0] = (bf16_t)v0.x; o[1] = (bf16_t)v0.y; o[2] = (bf16_t)v0.z; o[3] = (bf16_t)v0.w;
  o[4] = (bf16_t)v1.x; o[5] = (bf16_t)v1.y; o[6] = (bf16_t)v1.z; o[7] = (bf16_t)v1.w;
  *reinterpret_cast<bf16x8*>(out + (size_t)g * 8) = o;
}

// ---------------- W [K][N] fp32 -> Wt [N][K] bf16 ----------------
__global__ __launch_bounds__(256) void k_transpose_bf16(const float* __restrict__ W,
                                                        bf16_t* __restrict__ Wt,
                                                        int K, int N) {
  __shared__ float tile[32][33];
  int n0 = blockIdx.x * 32, k0 = blockIdx.y * 32;
  int tx = threadIdx.x, ty = threadIdx.y;
#pragma unroll
  for (int j = 0; j < 32; j += 8)
    tile[ty + j][tx] = W[(size_t)(k0 + ty + j) * N + n0 + tx];
  __syncthreads();
#pragma unroll
  for (int j = 0; j < 32; j += 8)
    Wt[(size_t)(n0 + ty + j) * K + k0 + tx] = (bf16_t)tile[tx][ty + j];
}

// ---------------- GEMM v3: 256x256 tile, BK=64, counted-vmcnt dbuf ----------------
// (unchanged from round 9 — known green)
template <bool OUT_BF16>
__global__ __launch_bounds__(512, 2) void k_gemm8(const bf16_t* __restrict__ A,
                                                  const bf16_t* __restrict__ Bt,
                                                  const float* __restrict__ bias,
                                                  void* __restrict__ Cout,
                                                  int N) {
  constexpr int K = 1280;
  constexpr int NT = K / 64;                     // 20 K-tiles
  __shared__ __align__(16) char smem[131072];    // [2][A 32KB | B 32KB]
  const int nb = N >> 8;
  const int cpx = (int)gridDim.x >> 3;           // grid % 8 == 0
  const int wg = ((int)blockIdx.x & 7) * cpx + ((int)blockIdx.x >> 3);
  const int bm = wg / nb, bn = wg % nb;
  const int tid = threadIdx.x, lane = tid & 63, w = tid >> 6;
  const int wm = w >> 2, wn = w & 3;             // 2 x 4 wave grid
  const int l15 = lane & 15, lg = lane >> 4;

  const bf16_t* Ab = A + (size_t)(bm * 256) * K;
  const bf16_t* Bb = Bt + (size_t)(bn * 256) * K;

  const int srow = w * 8 + (lane >> 3);
  const int scol = ((lane & 7) ^ (lane >> 3)) * 8;   // inverse-swizzled source chunk

  // --- bias preload, pinned: retire these VMEM ops before any staging ---
  float bv4[4];
#pragma unroll
  for (int nf = 0; nf < 4; ++nf)
    bv4[nf] = bias[bn * 256 + wn * 64 + nf * 16 + l15];
  asm volatile("" :: "v"(bv4[0]), "v"(bv4[1]), "v"(bv4[2]), "v"(bv4[3]) : "memory");
  asm volatile("s_waitcnt vmcnt(0)" ::: "memory");

  char* const sm = smem;
  auto stageA = [&](int buf, int g, int k0) {
    gload16(Ab + (size_t)(g * 64 + srow) * K + k0 + scol,
            sm + buf * 65536 + g * 8192 + w * 1024);
  };
  auto stageB = [&](int buf, int g, int k0) {
    gload16(Bb + (size_t)(g * 64 + srow) * K + k0 + scol,
            sm + buf * 65536 + 32768 + g * 8192 + w * 1024);
  };

  f32x4 acc[8][4];
#pragma unroll
  for (int i = 0; i < 8; ++i)
#pragma unroll
    for (int j = 0; j < 4; ++j) acc[i][j] = (f32x4){0.f, 0.f, 0.f, 0.f};

#pragma unroll
  for (int g = 0; g < 4; ++g) { stageA(0, g, 0); stageB(0, g, 0); }

#pragma unroll 1
  for (int T = 0; T < NT; ++T) {
    const int buf = T & 1, nbuf = buf ^ 1;
    const int k1 = (T + 1) * 64;
    if (T + 1 < NT) {
      stageA(nbuf, 0, k1);
      stageA(nbuf, 1, k1);
      // tile T's 8 loads forced complete; T+1's first 2 stay in flight
      asm volatile("s_waitcnt vmcnt(2)\n\ts_barrier" ::: "memory");
      stageA(nbuf, 2, k1); stageA(nbuf, 3, k1);
      stageB(nbuf, 0, k1); stageB(nbuf, 1, k1);
      stageB(nbuf, 2, k1); stageB(nbuf, 3, k1);
    } else {
      asm volatile("s_waitcnt vmcnt(0)\n\ts_barrier" ::: "memory");
    }
    const char* Abase = sm + buf * 65536;
    const char* Bbase = Abase + 32768;
#pragma unroll
    for (int kk = 0; kk < 2; ++kk) {
      const int cb = kk * 64 + lg * 16;
      bf16x8 bfv[4];
#pragma unroll
      for (int nf = 0; nf < 4; ++nf) {
        const int row = wn * 64 + nf * 16 + l15;
        bfv[nf] = *reinterpret_cast<const bf16x8*>(Bbase + row * 128 + (cb ^ ((row & 7) << 4)));
      }
#pragma unroll
      for (int mg = 0; mg < 2; ++mg) {
        bf16x8 af[4];
#pragma unroll
        for (int mf = 0; mf < 4; ++mf) {
          const int row = wm * 128 + mg * 64 + mf * 16 + l15;
          af[mf] = *reinterpret_cast<const bf16x8*>(Abase + row * 128 + (cb ^ ((row & 7) << 4)));
        }
        __builtin_amdgcn_s_setprio(1);
#pragma unroll
        for (int mf = 0; mf < 4; ++mf)
#pragma unroll
          for (int nf = 0; nf < 4; ++nf)
            acc[mg * 4 + mf][nf] =
                __builtin_amdgcn_mfma_f32_16x16x32_bf16(af[mf], bfv[nf], acc[mg * 4 + mf][nf], 0, 0, 0);
        __builtin_amdgcn_s_setprio(0);
      }
    }
  }

  const int rg = lg << 2;
#pragma unroll
  for (int nf = 0; nf < 4; ++nf) {
    const int col = bn * 256 + wn * 64 + nf * 16 + l15;
    const float bv = bv4[nf];
#pragma unroll
    for (int m8 = 0; m8 < 8; ++m8) {
      const int row0 = bm * 256 + wm * 128 + m8 * 16 + rg;
#pragma unroll
      for (int r = 0; r < 4; ++r) {
        float v = acc[m8][nf][r] + bv;
        if (OUT_BF16)
          reinterpret_cast<bf16_t*>(Cout)[(size_t)(row0 + r) * N + col] = (bf16_t)v;
        else
          reinterpret_cast<float*>(Cout)[(size_t)(row0 + r) * N + col] = v;
      }
    }
  }
}

// ---------------- RoPE (in-place; q additionally scaled by 1/sqrt(80)*log2e) ----------------
__global__ __launch_bounds__(256) void k_rope(bf16_t* __restrict__ qkv,
                                              const float* __restrict__ cosT,
                                              const float* __restrict__ sinT) {
  const float QS = 0.11180339887498949f * 1.4426950408889634f;
  int g = blockIdx.x * 256 + threadIdx.x;
  int c = g % 5;
  int h = (g / 5) & 15;
  int s = g / 80;
  const int d0 = c * 8;
  float cs[8], sn[8];
#pragma unroll
  for (int j = 0; j < 8; ++j) {
    cs[j] = cosT[s * 80 + d0 + j];
    sn[j] = sinT[s * 80 + d0 + j];
  }
  size_t base = (size_t)s * N_QKV + h * 80 + d0;
#pragma unroll
  for (int part = 0; part < 2; ++part) {
    const float sc = (part == 0) ? QS : 1.0f;
    bf16_t* p0 = qkv + base + part * 1280;
    bf16_t* p1 = p0 + 40;
    bf16x8 a = *reinterpret_cast<bf16x8*>(p0);
    bf16x8 b = *reinterpret_cast<bf16x8*>(p1);
    bf16x8 oa, ob;
#pragma unroll
    for (int j = 0; j < 8; ++j) {
      float x = (float)a[j], y = (float)b[j];
      oa[j] = (bf16_t)((x * cs[j] - y * sn[j]) * sc);
      ob[j] = (bf16_t)((y * cs[j] + x * sn[j]) * sc);
    }
    *reinterpret_cast<bf16x8*>(p0) = oa;
    *reinterpret_cast<bf16x8*>(p1) = ob;
  }
}

// ---------------- V transpose+permute: vtg[seg][h][d][kv'] = V[seg][swap23(kv')][h][d] ----------------
__global__ __launch_bounds__(256) void k_vtrans(const bf16_t* __restrict__ qkv,
                                                bf16_t* __restrict__ vtg) {
  __shared__ bf16_t T[64][88];
  int sh = blockIdx.x >> 4;            // seg*16 + h
  int kt = blockIdx.x & 15;
  int seg = sh >> 4, h = sh & 15;
  int kv0 = kt * 64;
  int tid = threadIdx.x;
#pragma unroll
  for (int i = 0; i < 3; ++i) {
    int c = tid + i * 256;
    if (c < 640) {
      int r = c / 10, ch = c - r * 10;
      *reinterpret_cast<uint4*>(&T[r][ch * 8]) =
        *reinterpret_cast<const uint4*>(qkv + (size_t)(seg * 1024 + kv0 + r) * N_QKV + 2 * DIM + h * 80 + ch * 8);
    }
  }
  __syncthreads();
#pragma unroll
  for (int i = 0; i < 3; ++i) {
    int c = tid + i * 256;
    if (c < 640) {
      int d = c >> 3, co = c & 7;
      bf16x8 o;
#pragma unroll
      for (int j = 0; j < 8; ++j) {
        int kp = co * 8 + j;
        int kv = (kp & ~12) | (((kp >> 2) & 1) << 3) | (((kp >> 3) & 1) << 2);  // swap bits 2,3
        o[j] = T[kv][d];
      }
      *reinterpret_cast<bf16x8*>(vtg + ((size_t)(sh * 80 + d)) * 1024 + kv0 + co * 8) = o;
    }
  }
}

// ---------------- V pad rows: vpad[0][*]=1.0 (sum row), vpad[1..15][*]=0 ----------------
__global__ __launch_bounds__(256) void k_padinit(bf16_t* __restrict__ vpad) {
  int g = blockIdx.x * 256 + threadIdx.x;        // 2048 x uint4 = 32 KB
  const uint4 ones4 = {0x3F803F80u, 0x3F803F80u, 0x3F803F80u, 0x3F803F80u};
  const uint4 z4 = {0u, 0u, 0u, 0u};
  reinterpret_cast<uint4*>(vpad)[g] = (g < 128) ? ones4 : z4;
}

// ---------------- flash attention v6: barrier-free, direct-global K/V ----------------
// 512 thr (8 waves x 32 q-rows). K/V tiles (10KB + 12KB) are read per-lane
// straight from global: all 8 waves touch the same tile -> L1-resident after
// first touch. No LDS staging, no issue/commit VALU, no __syncthreads in the
// main loop -> waves free-run; latency hidden by 16 independent waves/CU.
// Math/layouts identical to round 9 (sum-via-ones-row in o2, defer-max THR=6).
__global__ __launch_bounds__(512, 4) void k_attn2(const bf16_t* __restrict__ qkv,
                                                  const bf16_t* __restrict__ vtg,
                                                  const bf16_t* __restrict__ vpad,
                                                  bf16_t* __restrict__ outp) {
  __shared__ __align__(16) bf16_t Osm[256 * 88];   // epilogue transpose only (45056 B)

  const int bid = blockIdx.x;
  const int seg = bid & 7, qt = (bid >> 3) & 3, h = bid >> 5;
  const int tid = threadIdx.x, lane = tid & 63, w = tid >> 6;
  const int l31 = lane & 31, hi = lane >> 5;
  const int q0 = seg * 1024 + qt * 256;
  const int sh = seg * 16 + h;

  // Q fragments (B operand): lane l31 = q row, hi selects 8-elem half
  bf16x8 qf[5];
  {
    const bf16_t* qp = qkv + (size_t)(q0 + w * 32 + l31) * N_QKV + h * 80 + hi * 8;
#pragma unroll
    for (int ks = 0; ks < 5; ++ks) qf[ks] = *reinterpret_cast<const bf16x8*>(qp + ks * 16);
  }

  // per-lane A-operand row pointers (advance by one KV tile per iteration)
  const bf16_t* k0p = qkv + (size_t)(seg * 1024 + l31) * N_QKV + DIM + h * 80 + hi * 8;
  const bf16_t* k1p = k0p + (size_t)32 * N_QKV;
  const bf16_t* v0p = vtg + (size_t)(sh * 80 + l31) * 1024;
  const bf16_t* v1p = vtg + (size_t)(sh * 80 + 32 + l31) * 1024;
  const int r2 = 64 + l31;
  const bf16_t* v2p = (r2 < 80) ? (vtg + (size_t)(sh * 80 + r2) * 1024)
                                : (vpad + (size_t)(r2 - 80) * 1024);

  f32x16 o0, o1, o2;
#pragma unroll
  for (int r = 0; r < 16; ++r) { o0[r] = 0.f; o1[r] = 0.f; o2[r] = 0.f; }
  float mrun = -1e30f;

#pragma unroll 1
  for (int t = 0; t < 16; ++t) {
    // ---- S^T = K · Q^T ----
    f32x16 st0, st1;
#pragma unroll
    for (int r = 0; r < 16; ++r) { st0[r] = 0.f; st1[r] = 0.f; }
    __builtin_amdgcn_s_setprio(1);
#pragma unroll
    for (int ks = 0; ks < 5; ++ks) {
      bf16x8 a0 = *reinterpret_cast<const bf16x8*>(k0p + ks * 16);
      bf16x8 a1 = *reinterpret_cast<const bf16x8*>(k1p + ks * 16);
      st0 = __builtin_amdgcn_mfma_f32_32x32x16_bf16(a0, qf[ks], st0, 0, 0, 0);
      st1 = __builtin_amdgcn_mfma_f32_32x32x16_bf16(a1, qf[ks], st1, 0, 0, 0);
    }
    __builtin_amdgcn_s_setprio(0);

    // ---- online softmax: tree max + defer-max; sum rides in o2 (ones row) ----
    float mt[16];
#pragma unroll
    for (int r = 0; r < 16; ++r) mt[r] = fmaxf(st0[r], st1[r]);
#pragma unroll
    for (int s2 = 8; s2 >= 1; s2 >>= 1)
#pragma unroll
      for (int r = 0; r < s2; ++r) mt[r] = fmaxf(mt[r], mt[r + s2]);
    float mx = fmaxf(mt[0], __shfl_xor(mt[0], 32));
    if (!__all(mx <= mrun + 6.0f)) {             // THR=6 (base-2): P bounded by 64
      float mnew = fmaxf(mrun, mx);
      float corr = __builtin_exp2f(mrun - mnew);
      mrun = mnew;
#pragma unroll
      for (int r = 0; r < 16; ++r) { o0[r] *= corr; o1[r] *= corr; o2[r] *= corr; }
    }
#pragma unroll
    for (int r = 0; r < 16; ++r) st0[r] = __builtin_exp2f(st0[r] - mrun);
#pragma unroll
    for (int r = 0; r < 16; ++r) st1[r] = __builtin_exp2f(st1[r] - mrun);

    bf16x8 pb[4];
#pragma unroll
    for (int u = 0; u < 2; ++u)
#pragma unroll
      for (int j = 0; j < 8; ++j) {
        pb[u][j]     = (bf16_t)st0[u * 8 + j];
        pb[2 + u][j] = (bf16_t)st1[u * 8 + j];
      }

    // ---- O^T += V'^T · P' ----
    __builtin_amdgcn_s_setprio(1);
#pragma unroll
    for (int ks2 = 0; ks2 < 4; ++ks2) {
      const int off = ((ks2 << 1) | hi) << 3;
      bf16x8 b0 = *reinterpret_cast<const bf16x8*>(v0p + off);
      bf16x8 b1 = *reinterpret_cast<const bf16x8*>(v1p + off);
      bf16x8 b2 = *reinterpret_cast<const bf16x8*>(v2p + off);
      o0 = __builtin_amdgcn_mfma_f32_32x32x16_bf16(b0, pb[ks2], o0, 0, 0, 0);
      o1 = __builtin_amdgcn_mfma_f32_32x32x16_bf16(b1, pb[ks2], o1, 0, 0, 0);
      o2 = __builtin_amdgcn_mfma_f32_32x32x16_bf16(b2, pb[ks2], o2, 0, 0, 0);
    }
    __builtin_amdgcn_s_setprio(0);

    k0p += (size_t)64 * N_QKV;
    k1p += (size_t)64 * N_QKV;
    v0p += 64; v1p += 64; v2p += 64;
  }

  // ---- normalize: sum(P) is o2 reg 8 (row 80) on hi=0 lanes; hi=1 holds 0 ----
  float sp = o2[8] + __shfl_xor(o2[8], 32);
  float inv = 1.0f / sp;

  const int qrow = w * 32 + l31;
#pragma unroll
  for (int r = 0; r < 16; ++r) {
    int crow = (r & 3) + 8 * (r >> 2) + 4 * hi;
    Osm[qrow * 88 + crow]      = (bf16_t)(o0[r] * inv);
    Osm[qrow * 88 + 32 + crow] = (bf16_t)(o1[r] * inv);
    if (r < 8) Osm[qrow * 88 + 64 + crow] = (bf16_t)(o2[r] * inv);
  }
  __syncthreads();
#pragma unroll
  for (int i = 0; i < 5; ++i) {
    int c = tid + i * 512;
    int q = c / 10, ch = c - q * 10;
    uint4 v = *reinterpret_cast<const uint4*>(Osm + q * 88 + ch * 8);
    *reinterpret_cast<uint4*>(outp + (size_t)(q0 + q) * DIM + h * 80 + ch * 8) = v;
  }
}

// ---------------- launch ----------------
extern "C" void kernel_launch(void* const* d_in, const int* in_sizes, int n_in,
                              void* d_out, int out_size, void* d_ws, size_t ws_size,
                              hipStream_t stream) {
  const float* hs    = (const float*)d_in[0];
  const float* cosT  = (const float*)d_in[1];
  const float* sinT  = (const float*)d_in[2];
  const float* Wqkv  = (const float*)d_in[3];
  const float* bqkv  = (const float*)d_in[4];
  const float* Wproj = (const float*)d_in[5];
  const float* bproj = (const float*)d_in[6];
  (void)in_sizes; (void)n_in; (void)out_size; (void)ws_size;

  char* ws = (char*)d_ws;
  bf16_t* hsb  = (bf16_t*)(ws);                    // 20,971,520 B (reused as vtg after GEMM)
  bf16_t* w1t  = (bf16_t*)(ws + 20971520);         //  9,830,400  (dead after QKV GEMM)
  bf16_t* w2t  = (bf16_t*)(ws + 30801920);         //  3,276,800
  bf16_t* qkvb = (bf16_t*)(ws + 34078720);         // 62,914,560
  bf16_t* attn = (bf16_t*)(ws + 96993280);         // 20,971,520
  bf16_t* vtg  = hsb;
  bf16_t* vpad = w1t;                              // 32 KB carved from dead w1t

  k_conv_bf16<<<5120, 256, 0, stream>>>(hs, hsb);
  k_transpose_bf16<<<dim3(120, 40), dim3(32, 8), 0, stream>>>(Wqkv, w1t, 1280, 3840);
  k_transpose_bf16<<<dim3(40, 40), dim3(32, 8), 0, stream>>>(Wproj, w2t, 1280, 1280);
  k_gemm8<true><<<480, 512, 0, stream>>>(hsb, w1t, bqkv, (void*)qkvb, 3840);
  k_rope<<<2560, 256, 0, stream>>>(qkvb, cosT, sinT);
  k_vtrans<<<2048, 256, 0, stream>>>(qkvb, vtg);
  k_padinit<<<8, 256, 0, stream>>>(vpad);
  k_attn2<<<512, 512, 0, stream>>>(qkvb, vtg, vpad, attn);
  k_gemm8<false><<<160, 512, 0, stream>>>(attn, w2t, bproj, d_out, 1280);
}

// Round 11
// 250.050 us; speedup vs baseline: 1.2914x; 1.2914x over previous
//
#include <hip/hip_runtime.h>
#include <hip/hip_bf16.h>
#include <stdint.h>

typedef __bf16 bf16_t;
typedef __bf16 bf16x8 __attribute__((ext_vector_type(8)));
typedef float f32x4 __attribute__((ext_vector_type(4)));
typedef float f32x16 __attribute__((ext_vector_type(16)));

#define S_TOK 8192
#define DIM   1280
#define NH    16
#define HD    80
#define LSEQ  1024
#define N_QKV 3840

// async global->LDS, 16B per lane; lds dest is wave-uniform base + lane*16
__device__ __forceinline__ void gload16(const bf16_t* g, void* l) {
  __builtin_amdgcn_global_load_lds(
      (__attribute__((address_space(1))) uint32_t*)g,
      (__attribute__((address_space(3))) uint32_t*)l, 16, 0, 0);
}

// ---------------- fp32 -> bf16 convert (hidden_states) ----------------
__global__ __launch_bounds__(256) void k_conv_bf16(const float* __restrict__ in,
                                                   bf16_t* __restrict__ out) {
  int g = blockIdx.x * 256 + threadIdx.x;
  const float4* p = reinterpret_cast<const float4*>(in) + (size_t)g * 2;
  float4 v0 = p[0], v1 = p[1];
  bf16x8 o;
  o[0] = (bf16_t)v0.x; o[1] = (bf16_t)v0.y; o[2] = (bf16_t)v0.z; o[3] = (bf16_t)v0.w;
  o[4] = (bf16_t)v1.x; o[5] = (bf16_t)v1.y; o[6] = (bf16_t)v1.z; o[7] = (bf16_t)v1.w;
  *reinterpret_cast<bf16x8*>(out + (size_t)g * 8) = o;
}

// ---------------- W [K][N] fp32 -> Wt [N][K] bf16 ----------------
__global__ __launch_bounds__(256) void k_transpose_bf16(const float* __restrict__ W,
                                                        bf16_t* __restrict__ Wt,
                                                        int K, int N) {
  __shared__ float tile[32][33];
  int n0 = blockIdx.x * 32, k0 = blockIdx.y * 32;
  int tx = threadIdx.x, ty = threadIdx.y;
#pragma unroll
  for (int j = 0; j < 32; j += 8)
    tile[ty + j][tx] = W[(size_t)(k0 + ty + j) * N + n0 + tx];
  __syncthreads();
#pragma unroll
  for (int j = 0; j < 32; j += 8)
    Wt[(size_t)(n0 + ty + j) * K + k0 + tx] = (bf16_t)tile[tx][ty + j];
}

// ---------------- GEMM v3: 256x256 tile, BK=64, counted-vmcnt dbuf ----------------
// (unchanged from round 9 — known green)
template <bool OUT_BF16>
__global__ __launch_bounds__(512, 2) void k_gemm8(const bf16_t* __restrict__ A,
                                                  const bf16_t* __restrict__ Bt,
                                                  const float* __restrict__ bias,
                                                  void* __restrict__ Cout,
                                                  int N) {
  constexpr int K = 1280;
  constexpr int NT = K / 64;                     // 20 K-tiles
  __shared__ __align__(16) char smem[131072];    // [2][A 32KB | B 32KB]
  const int nb = N >> 8;
  const int cpx = (int)gridDim.x >> 3;           // grid % 8 == 0
  const int wg = ((int)blockIdx.x & 7) * cpx + ((int)blockIdx.x >> 3);
  const int bm = wg / nb, bn = wg % nb;
  const int tid = threadIdx.x, lane = tid & 63, w = tid >> 6;
  const int wm = w >> 2, wn = w & 3;             // 2 x 4 wave grid
  const int l15 = lane & 15, lg = lane >> 4;

  const bf16_t* Ab = A + (size_t)(bm * 256) * K;
  const bf16_t* Bb = Bt + (size_t)(bn * 256) * K;

  const int srow = w * 8 + (lane >> 3);
  const int scol = ((lane & 7) ^ (lane >> 3)) * 8;   // inverse-swizzled source chunk

  // --- bias preload, pinned: retire these VMEM ops before any staging ---
  float bv4[4];
#pragma unroll
  for (int nf = 0; nf < 4; ++nf)
    bv4[nf] = bias[bn * 256 + wn * 64 + nf * 16 + l15];
  asm volatile("" :: "v"(bv4[0]), "v"(bv4[1]), "v"(bv4[2]), "v"(bv4[3]) : "memory");
  asm volatile("s_waitcnt vmcnt(0)" ::: "memory");

  char* const sm = smem;
  auto stageA = [&](int buf, int g, int k0) {
    gload16(Ab + (size_t)(g * 64 + srow) * K + k0 + scol,
            sm + buf * 65536 + g * 8192 + w * 1024);
  };
  auto stageB = [&](int buf, int g, int k0) {
    gload16(Bb + (size_t)(g * 64 + srow) * K + k0 + scol,
            sm + buf * 65536 + 32768 + g * 8192 + w * 1024);
  };

  f32x4 acc[8][4];
#pragma unroll
  for (int i = 0; i < 8; ++i)
#pragma unroll
    for (int j = 0; j < 4; ++j) acc[i][j] = (f32x4){0.f, 0.f, 0.f, 0.f};

#pragma unroll
  for (int g = 0; g < 4; ++g) { stageA(0, g, 0); stageB(0, g, 0); }

#pragma unroll 1
  for (int T = 0; T < NT; ++T) {
    const int buf = T & 1, nbuf = buf ^ 1;
    const int k1 = (T + 1) * 64;
    if (T + 1 < NT) {
      stageA(nbuf, 0, k1);
      stageA(nbuf, 1, k1);
      // tile T's 8 loads forced complete; T+1's first 2 stay in flight
      asm volatile("s_waitcnt vmcnt(2)\n\ts_barrier" ::: "memory");
      stageA(nbuf, 2, k1); stageA(nbuf, 3, k1);
      stageB(nbuf, 0, k1); stageB(nbuf, 1, k1);
      stageB(nbuf, 2, k1); stageB(nbuf, 3, k1);
    } else {
      asm volatile("s_waitcnt vmcnt(0)\n\ts_barrier" ::: "memory");
    }
    const char* Abase = sm + buf * 65536;
    const char* Bbase = Abase + 32768;
#pragma unroll
    for (int kk = 0; kk < 2; ++kk) {
      const int cb = kk * 64 + lg * 16;
      bf16x8 bfv[4];
#pragma unroll
      for (int nf = 0; nf < 4; ++nf) {
        const int row = wn * 64 + nf * 16 + l15;
        bfv[nf] = *reinterpret_cast<const bf16x8*>(Bbase + row * 128 + (cb ^ ((row & 7) << 4)));
      }
#pragma unroll
      for (int mg = 0; mg < 2; ++mg) {
        bf16x8 af[4];
#pragma unroll
        for (int mf = 0; mf < 4; ++mf) {
          const int row = wm * 128 + mg * 64 + mf * 16 + l15;
          af[mf] = *reinterpret_cast<const bf16x8*>(Abase + row * 128 + (cb ^ ((row & 7) << 4)));
        }
        __builtin_amdgcn_s_setprio(1);
#pragma unroll
        for (int mf = 0; mf < 4; ++mf)
#pragma unroll
          for (int nf = 0; nf < 4; ++nf)
            acc[mg * 4 + mf][nf] =
                __builtin_amdgcn_mfma_f32_16x16x32_bf16(af[mf], bfv[nf], acc[mg * 4 + mf][nf], 0, 0, 0);
        __builtin_amdgcn_s_setprio(0);
      }
    }
  }

  const int rg = lg << 2;
#pragma unroll
  for (int nf = 0; nf < 4; ++nf) {
    const int col = bn * 256 + wn * 64 + nf * 16 + l15;
    const float bv = bv4[nf];
#pragma unroll
    for (int m8 = 0; m8 < 8; ++m8) {
      const int row0 = bm * 256 + wm * 128 + m8 * 16 + rg;
#pragma unroll
      for (int r = 0; r < 4; ++r) {
        float v = acc[m8][nf][r] + bv;
        if (OUT_BF16)
          reinterpret_cast<bf16_t*>(Cout)[(size_t)(row0 + r) * N + col] = (bf16_t)v;
        else
          reinterpret_cast<float*>(Cout)[(size_t)(row0 + r) * N + col] = v;
      }
    }
  }
}

// ---------------- RoPE (in-place; q additionally scaled by 1/sqrt(80)*log2e) ----------------
__global__ __launch_bounds__(256) void k_rope(bf16_t* __restrict__ qkv,
                                              const float* __restrict__ cosT,
                                              const float* __restrict__ sinT) {
  const float QS = 0.11180339887498949f * 1.4426950408889634f;
  int g = blockIdx.x * 256 + threadIdx.x;
  int c = g % 5;
  int h = (g / 5) & 15;
  int s = g / 80;
  const int d0 = c * 8;
  float cs[8], sn[8];
#pragma unroll
  for (int j = 0; j < 8; ++j) {
    cs[j] = cosT[s * 80 + d0 + j];
    sn[j] = sinT[s * 80 + d0 + j];
  }
  size_t base = (size_t)s * N_QKV + h * 80 + d0;
#pragma unroll
  for (int part = 0; part < 2; ++part) {
    const float sc = (part == 0) ? QS : 1.0f;
    bf16_t* p0 = qkv + base + part * 1280;
    bf16_t* p1 = p0 + 40;
    bf16x8 a = *reinterpret_cast<bf16x8*>(p0);
    bf16x8 b = *reinterpret_cast<bf16x8*>(p1);
    bf16x8 oa, ob;
#pragma unroll
    for (int j = 0; j < 8; ++j) {
      float x = (float)a[j], y = (float)b[j];
      oa[j] = (bf16_t)((x * cs[j] - y * sn[j]) * sc);
      ob[j] = (bf16_t)((y * cs[j] + x * sn[j]) * sc);
    }
    *reinterpret_cast<bf16x8*>(p0) = oa;
    *reinterpret_cast<bf16x8*>(p1) = ob;
  }
}

// ---------------- V transpose+permute: vtg[seg][h][d][kv'] = V[seg][swap23(kv')][h][d] ----------------
__global__ __launch_bounds__(256) void k_vtrans(const bf16_t* __restrict__ qkv,
                                                bf16_t* __restrict__ vtg) {
  __shared__ bf16_t T[64][88];
  int sh = blockIdx.x >> 4;            // seg*16 + h
  int kt = blockIdx.x & 15;
  int seg = sh >> 4, h = sh & 15;
  int kv0 = kt * 64;
  int tid = threadIdx.x;
#pragma unroll
  for (int i = 0; i < 3; ++i) {
    int c = tid + i * 256;
    if (c < 640) {
      int r = c / 10, ch = c - r * 10;
      *reinterpret_cast<uint4*>(&T[r][ch * 8]) =
        *reinterpret_cast<const uint4*>(qkv + (size_t)(seg * 1024 + kv0 + r) * N_QKV + 2 * DIM + h * 80 + ch * 8);
    }
  }
  __syncthreads();
#pragma unroll
  for (int i = 0; i < 3; ++i) {
    int c = tid + i * 256;
    if (c < 640) {
      int d = c >> 3, co = c & 7;
      bf16x8 o;
#pragma unroll
      for (int j = 0; j < 8; ++j) {
        int kp = co * 8 + j;
        int kv = (kp & ~12) | (((kp >> 2) & 1) << 3) | (((kp >> 3) & 1) << 2);  // swap bits 2,3
        o[j] = T[kv][d];
      }
      *reinterpret_cast<bf16x8*>(vtg + ((size_t)(sh * 80 + d)) * 1024 + kv0 + co * 8) = o;
    }
  }
}

// ---------------- flash attention v7: lagged-PV pipeline (QK(t) || PV(t-1) || SM) ----------------
// 512 thr (8 waves x 32 q-rows), KVBLK=64. K: 2 x [64][128] slot-XOR swizzled;
// V: 3 buffers (PV reads tile t-1 while commit writes t+1). PV(t-1) MFMAs are
// issued BEFORE SM(t)'s VALU/exp2 work: with defer-max the o-rescale is usually
// skipped, so SM(t) has no dependence on PV(t-1) -> matrix pipe runs under VALU.
__global__ __launch_bounds__(512, 2) void k_attn2(const bf16_t* __restrict__ qkv,
                                                  const bf16_t* __restrict__ vtg,
                                                  bf16_t* __restrict__ outp) {
  __shared__ __align__(16) char smem[69632];
  bf16_t* KsB = (bf16_t*)smem;                 // 2 x [64][128]  (8192 elems per buf)
  bf16_t* VsB = (bf16_t*)(smem + 32768);       // 3 x [96][64]   (6144 elems per buf)

  const int bid = blockIdx.x;
  const int seg = bid & 7, qt = (bid >> 3) & 3, h = bid >> 5;
  const int tid = threadIdx.x, lane = tid & 63, w = tid >> 6;
  const int l31 = lane & 31, hi = lane >> 5;
  const int sw = l31 & 7;                      // row-XOR key (rows l31+32k share it)
  const int q0 = seg * 1024 + qt * 256;

  const bf16_t* kbase = qkv + ((size_t)seg * 1024) * N_QKV + DIM + h * 80;
  const bf16_t* vbase = vtg + ((size_t)(seg * 16 + h) * 80) * 1024;

  bf16x8 qf[5];
  {
    const bf16_t* qp = qkv + (size_t)(q0 + w * 32 + l31) * N_QKV + h * 80 + hi * 8;
#pragma unroll
    for (int ks = 0; ks < 5; ++ks) qf[ks] = *reinterpret_cast<const bf16x8*>(qp + ks * 16);
  }

  const uint4 ones4 = {0x3F803F80u, 0x3F803F80u, 0x3F803F80u, 0x3F803F80u};  // bf16 1.0 x8
  uint4 kreg[2], vreg[2];
  auto issue = [&](int kv0) {
#pragma unroll
    for (int i = 0; i < 2; ++i) {
      int c = tid + i * 512;
      if (c < 640) {
        int r = c / 10, ch = c - r * 10;
        kreg[i] = *reinterpret_cast<const uint4*>(kbase + (size_t)(kv0 + r) * N_QKV + ch * 8);
      }
    }
#pragma unroll
    for (int i = 0; i < 2; ++i) {
      int c = tid + i * 512;
      if (c < 768) {
        int d = c >> 3, ch = c & 7;
        uint4 v = {0u, 0u, 0u, 0u};
        if (d < 80) v = *reinterpret_cast<const uint4*>(vbase + (size_t)d * 1024 + kv0 + ch * 8);
        else if (d == 80) v = ones4;           // ones row -> o2 row 80 = sum(P)
        vreg[i] = v;
      }
    }
  };
  auto commit = [&](int kb, int vb) {
    bf16_t* Kb = KsB + kb * 8192;
    bf16_t* Vb = VsB + vb * 6144;
#pragma unroll
    for (int i = 0; i < 2; ++i) {
      int c = tid + i * 512;
      if (c < 640) {
        int r = c / 10, ch = c - r * 10;
        *reinterpret_cast<uint4*>(Kb + r * 128 + ((ch ^ (r & 7)) << 3)) = kreg[i];
      }
    }
#pragma unroll
    for (int i = 0; i < 2; ++i) {
      int c = tid + i * 512;
      if (c < 768) {
        int d = c >> 3, ch = c & 7;
        *reinterpret_cast<uint4*>(Vb + d * 64 + ((ch ^ (d & 7)) << 3)) = vreg[i];
      }
    }
  };

  f32x16 o0, o1, o2;
#pragma unroll
  for (int r = 0; r < 16; ++r) { o0[r] = 0.f; o1[r] = 0.f; o2[r] = 0.f; }
  float mrun = -1e30f;
  f32x16 st0, st1;
  bf16x8 pb[4];

  auto qk = [&](int kb) {
#pragma unroll
    for (int r = 0; r < 16; ++r) { st0[r] = 0.f; st1[r] = 0.f; }
    const bf16_t* Kb = KsB + kb * 8192;
    __builtin_amdgcn_s_setprio(1);
#pragma unroll
    for (int ks = 0; ks < 5; ++ks) {
      const int so = (((ks << 1) | hi) ^ sw) << 3;
      bf16x8 k0 = *reinterpret_cast<const bf16x8*>(Kb + l31 * 128 + so);
      bf16x8 k1 = *reinterpret_cast<const bf16x8*>(Kb + (32 + l31) * 128 + so);
      st0 = __builtin_amdgcn_mfma_f32_32x32x16_bf16(k0, qf[ks], st0, 0, 0, 0);
      st1 = __builtin_amdgcn_mfma_f32_32x32x16_bf16(k1, qf[ks], st1, 0, 0, 0);
    }
    __builtin_amdgcn_s_setprio(0);
  };
  auto pv = [&](int vb) {
    const bf16_t* Vb = VsB + vb * 6144;
    __builtin_amdgcn_s_setprio(1);
#pragma unroll
    for (int ks2 = 0; ks2 < 4; ++ks2) {
      const int so = (((ks2 << 1) | hi) ^ sw) << 3;
      bf16x8 v0 = *reinterpret_cast<const bf16x8*>(Vb + l31 * 64 + so);
      bf16x8 v1 = *reinterpret_cast<const bf16x8*>(Vb + (32 + l31) * 64 + so);
      bf16x8 v2 = *reinterpret_cast<const bf16x8*>(Vb + (64 + l31) * 64 + so);
      o0 = __builtin_amdgcn_mfma_f32_32x32x16_bf16(v0, pb[ks2], o0, 0, 0, 0);
      o1 = __builtin_amdgcn_mfma_f32_32x32x16_bf16(v1, pb[ks2], o1, 0, 0, 0);
      o2 = __builtin_amdgcn_mfma_f32_32x32x16_bf16(v2, pb[ks2], o2, 0, 0, 0);
    }
    __builtin_amdgcn_s_setprio(0);
  };
  auto softmax_pack = [&]() {
    float mt[16];
#pragma unroll
    for (int r = 0; r < 16; ++r) mt[r] = fmaxf(st0[r], st1[r]);
#pragma unroll
    for (int s2 = 8; s2 >= 1; s2 >>= 1)
#pragma unroll
      for (int r = 0; r < s2; ++r) mt[r] = fmaxf(mt[r], mt[r + s2]);
    float mx = fmaxf(mt[0], __shfl_xor(mt[0], 32));
    if (!__all(mx <= mrun + 6.0f)) {           // THR=6 (base-2): P bounded by 64
      float mnew = fmaxf(mrun, mx);
      float corr = __builtin_exp2f(mrun - mnew);
      mrun = mnew;
#pragma unroll
      for (int r = 0; r < 16; ++r) { o0[r] *= corr; o1[r] *= corr; o2[r] *= corr; }
    }
#pragma unroll
    for (int r = 0; r < 16; ++r) st0[r] = __builtin_exp2f(st0[r] - mrun);
#pragma unroll
    for (int r = 0; r < 16; ++r) st1[r] = __builtin_exp2f(st1[r] - mrun);
#pragma unroll
    for (int u = 0; u < 2; ++u)
#pragma unroll
      for (int j = 0; j < 8; ++j) {
        pb[u][j]     = (bf16_t)st0[u * 8 + j];
        pb[2 + u][j] = (bf16_t)st1[u * 8 + j];
      }
  };

  // prologue: tile 0 staged; QK(0)+SM(0) packed, PV deferred one tile
  issue(0);
  commit(0, 0);
  __syncthreads();
  issue(64);
  qk(0);
  softmax_pack();
  commit(1, 1);
  __syncthreads();

#pragma unroll 1
  for (int t = 1; t < 16; ++t) {
    if (t < 15) issue((t + 1) * 64);
    qk(t & 1);                                 // S(t): MFMA pipe
    pv((t - 1) % 3);                           // PV(t-1): MFMA pipe, indep of st
    softmax_pack();                            // SM(t): VALU, overlaps PV MFMAs
    if (t < 15) commit((t + 1) & 1, (t + 1) % 3);
    __syncthreads();
  }
  pv(0);                                       // PV(15), Vbuf 15%3 == 0
  __syncthreads();                             // V reads done before Osm overwrites

  // ---- normalize: sum(P) is o2 reg 8 (row 80) on hi=0 lanes; hi=1 holds 0 ----
  float sp = o2[8] + __shfl_xor(o2[8], 32);
  float inv = 1.0f / sp;

  bf16_t* Osm = (bf16_t*)smem;  // [256][88]
  const int qrow = w * 32 + l31;
#pragma unroll
  for (int r = 0; r < 16; ++r) {
    int crow = (r & 3) + 8 * (r >> 2) + 4 * hi;
    Osm[qrow * 88 + crow]      = (bf16_t)(o0[r] * inv);
    Osm[qrow * 88 + 32 + crow] = (bf16_t)(o1[r] * inv);
    if (r < 8) Osm[qrow * 88 + 64 + crow] = (bf16_t)(o2[r] * inv);
  }
  __syncthreads();
#pragma unroll
  for (int i = 0; i < 5; ++i) {
    int c = tid + i * 512;
    int q = c / 10, ch = c - q * 10;
    uint4 v = *reinterpret_cast<const uint4*>(Osm + q * 88 + ch * 8);
    *reinterpret_cast<uint4*>(outp + (size_t)(q0 + q) * DIM + h * 80 + ch * 8) = v;
  }
}

// ---------------- launch ----------------
extern "C" void kernel_launch(void* const* d_in, const int* in_sizes, int n_in,
                              void* d_out, int out_size, void* d_ws, size_t ws_size,
                              hipStream_t stream) {
  const float* hs    = (const float*)d_in[0];
  const float* cosT  = (const float*)d_in[1];
  const float* sinT  = (const float*)d_in[2];
  const float* Wqkv  = (const float*)d_in[3];
  const float* bqkv  = (const float*)d_in[4];
  const float* Wproj = (const float*)d_in[5];
  const float* bproj = (const float*)d_in[6];
  (void)in_sizes; (void)n_in; (void)out_size; (void)ws_size;

  char* ws = (char*)d_ws;
  bf16_t* hsb  = (bf16_t*)(ws);                    // 20,971,520 B (reused as vtg after GEMM)
  bf16_t* w1t  = (bf16_t*)(ws + 20971520);         //  9,830,400
  bf16_t* w2t  = (bf16_t*)(ws + 30801920);         //  3,276,800
  bf16_t* qkvb = (bf16_t*)(ws + 34078720);         // 62,914,560
  bf16_t* attn = (bf16_t*)(ws + 96993280);         // 20,971,520
  bf16_t* vtg  = hsb;

  k_conv_bf16<<<5120, 256, 0, stream>>>(hs, hsb);
  k_transpose_bf16<<<dim3(120, 40), dim3(32, 8), 0, stream>>>(Wqkv, w1t, 1280, 3840);
  k_transpose_bf16<<<dim3(40, 40), dim3(32, 8), 0, stream>>>(Wproj, w2t, 1280, 1280);
  k_gemm8<true><<<480, 512, 0, stream>>>(hsb, w1t, bqkv, (void*)qkvb, 3840);
  k_rope<<<2560, 256, 0, stream>>>(qkvb, cosT, sinT);
  k_vtrans<<<2048, 256, 0, stream>>>(qkvb, vtg);
  k_attn2<<<512, 512, 0, stream>>>(qkvb, vtg, attn);
  k_gemm8<false><<<160, 512, 0, stream>>>(attn, w2t, bproj, d_out, 1280);
}